// Round 1
// baseline (11798.632 us; speedup 1.0000x reference)
//
#include <hip/hip_runtime.h>
#include <hip/hip_bf16.h>

// LSTM + Gaussian attention window (Graves), B=64, T=512, H=512, K=10, NC=80, U=64.
// Persistent cooperative-style kernel: 128 blocks x 256 threads, each block owns
// 4 h-columns (16 gate columns). One custom grid barrier per timestep.
// h broadcast via double-buffered bf16 buffer in d_ws; p/kappa/phi/w recomputed
// redundantly per block (p folded into the same MFMA K-loop as gates).

#define GRID_BLOCKS 128
#define TPB 256

typedef __attribute__((ext_vector_type(8))) __bf16 bf16x8;
typedef __attribute__((ext_vector_type(4))) float f32x4;

struct Smem {
    // Pre-swizzled MFMA B-fragments: [chunk][lane][8 bf16] -> lane reads 16B contiguous
    alignas(16) __bf16 bG[19 * 64 * 8];      // gates: 16 h-chunks + 3 w-chunks (K pad 96)
    alignas(16) __bf16 bP[2 * 16 * 64 * 8];  // window: 2 N-tiles x 16 h-chunks
    alignas(16) __bf16 wBf[64 * 104];        // w as bf16, padded row stride 104
    float P[64 * 33];                        // p scatter (30 cols used), stride 33
    float Gt[64 * 17];                       // gate scatter, stride 17
    float Al[64 * 10];
    float Be[64 * 10];
    float Ka[64 * 10];                       // kappa state (replicated per block)
    float Wacc[64 * 80];                     // w accumulator fp32
    float Xt[64 * 3];
    float Maskv[64 * 64];
    float Wx[16 * 3];
    float Bsum[16];
    float Bwin[32];
    int   Act[64];
    unsigned char Sent[64 * 64];
};

__device__ __forceinline__ float sigf(float x) {
    return 1.f / (1.f + __expf(-x));
}
__device__ __forceinline__ float tanh_fast(float x) {
    float xx = fminf(fmaxf(x, -15.f), 15.f);
    float e = __expf(2.f * xx);
    return (e - 1.f) / (e + 1.f);
}

__device__ __forceinline__ void grid_barrier(int* cnt, int* gen) {
    __syncthreads();
    if (threadIdx.x == 0) {
        __threadfence();
        int g = __hip_atomic_load(gen, __ATOMIC_RELAXED, __HIP_MEMORY_SCOPE_AGENT);
        int old = __hip_atomic_fetch_add(cnt, 1, __ATOMIC_ACQ_REL, __HIP_MEMORY_SCOPE_AGENT);
        if (old == GRID_BLOCKS - 1) {
            __hip_atomic_store(cnt, 0, __ATOMIC_RELAXED, __HIP_MEMORY_SCOPE_AGENT);
            __hip_atomic_fetch_add(gen, 1, __ATOMIC_ACQ_REL, __HIP_MEMORY_SCOPE_AGENT);
        } else {
            while (__hip_atomic_load(gen, __ATOMIC_ACQUIRE, __HIP_MEMORY_SCOPE_AGENT) == g) {
                __builtin_amdgcn_s_sleep(1);
            }
        }
        __threadfence();
    }
    __syncthreads();
}

__global__ void init_ws_kernel(int* ws) {
    // zero h double-buffer (131072 B) + barrier (8 B)
    int idx = blockIdx.x * TPB + threadIdx.x;
    if (idx < 32770) ws[idx] = 0;
}

__global__ void __launch_bounds__(TPB, 1) lstm_attn(
    const float* __restrict__ strokes,    // [64][512][3]
    const int*   __restrict__ sentences,  // [64][64]
    const float* __restrict__ smask,      // [64][64]
    const float* __restrict__ Wih,        // [2048][83]
    const float* __restrict__ Whh,        // [2048][512]
    const float* __restrict__ bih,        // [2048]
    const float* __restrict__ bhh,        // [2048]
    const float* __restrict__ Wwin,       // [30][512]
    const float* __restrict__ bwin,       // [30]
    float* __restrict__ out,              // hs [64][512][512] ++ ws [64][512][80]
    __bf16* __restrict__ hbuf,            // [2][64][512] bf16
    int* __restrict__ bar)
{
    __shared__ Smem S;
    const int tid  = threadIdx.x;
    const int blk  = blockIdx.x;
    const int lane = tid & 63;
    const int wave = tid >> 6;
    const int lm   = lane & 15;   // MFMA col index within tile / A row
    const int quad = lane >> 4;   // MFMA k-block
    const int myb  = wave * 16 + lm;  // batch row this lane loads for A

    // ------------- one-time init: pre-swizzle weights into LDS -------------
    for (int idx = tid; idx < 19 * 64 * 8; idx += TPB) {
        int kc = idx >> 9;
        int L  = (idx >> 3) & 63;
        int j  = idx & 7;
        int n  = L & 15;
        int colg = (n >> 2) * 512 + blk * 4 + (n & 3);  // gate-major column
        float v;
        if (kc < 16) {
            int k = kc * 32 + (L >> 4) * 8 + j;
            v = Whh[colg * 512 + k];
        } else {
            int k = (kc - 16) * 32 + (L >> 4) * 8 + j;
            v = (k < 80) ? Wih[colg * 83 + 3 + k] : 0.f;
        }
        S.bG[idx] = (__bf16)v;
    }
    for (int idx = tid; idx < 2 * 16 * 64 * 8; idx += TPB) {
        int nt = idx >> 13;
        int kc = (idx >> 9) & 15;
        int L  = (idx >> 3) & 63;
        int j  = idx & 7;
        int r  = nt * 16 + (L & 15);
        int k  = kc * 32 + (L >> 4) * 8 + j;
        S.bP[idx] = (__bf16)((r < 30) ? Wwin[r * 512 + k] : 0.f);
    }
    for (int idx = tid; idx < 64 * 64; idx += TPB) {
        S.Sent[idx]  = (unsigned char)sentences[idx];
        S.Maskv[idx] = smask[idx];
    }
    if (tid < 16) {
        int colg = (tid >> 2) * 512 + blk * 4 + (tid & 3);
        S.Bsum[tid] = bih[colg] + bhh[colg];
        S.Wx[tid * 3 + 0] = Wih[colg * 83 + 0];
        S.Wx[tid * 3 + 1] = Wih[colg * 83 + 1];
        S.Wx[tid * 3 + 2] = Wih[colg * 83 + 2];
    }
    if (tid < 32) S.Bwin[tid] = (tid < 30) ? bwin[tid] : 0.f;
    for (int idx = tid; idx < 640; idx += TPB) S.Ka[idx] = 0.f;
    for (int idx = tid; idx < 64 * 104; idx += TPB) S.wBf[idx] = (__bf16)0.f;
    float c_state = 0.f;  // cell state for (b = tid>>2, ml = tid&3)
    __syncthreads();

    // ------------- main time loop -------------
    for (int t = 0; t <= 512; ++t) {
        // phase 1: K-loop over 16 h-chunks; shared A feeds gates + both p tiles
        const __bf16* hsrc = hbuf + ((t + 1) & 1) * (64 * 512);
        const __bf16* arow = hsrc + myb * 512 + quad * 8;
        f32x4 accG;
        accG[0] = accG[1] = accG[2] = accG[3] = S.Bsum[lm];
        f32x4 accP0 = {0.f, 0.f, 0.f, 0.f};
        f32x4 accP1 = {0.f, 0.f, 0.f, 0.f};
        #pragma unroll 4
        for (int kc = 0; kc < 16; ++kc) {
            bf16x8 a   = *(const bf16x8*)(arow + kc * 32);
            bf16x8 bg  = *(const bf16x8*)(&S.bG[(kc * 64 + lane) * 8]);
            bf16x8 bp0 = *(const bf16x8*)(&S.bP[((0 * 16 + kc) * 64 + lane) * 8]);
            bf16x8 bp1 = *(const bf16x8*)(&S.bP[((1 * 16 + kc) * 64 + lane) * 8]);
            accG  = __builtin_amdgcn_mfma_f32_16x16x32_bf16(a, bg,  accG,  0, 0, 0);
            accP0 = __builtin_amdgcn_mfma_f32_16x16x32_bf16(a, bp0, accP0, 0, 0, 0);
            accP1 = __builtin_amdgcn_mfma_f32_16x16x32_bf16(a, bp1, accP1, 0, 0, 0);
        }

        // phase 2: scatter p (+b_win), zero w accumulator, clear active, stage x_t
        #pragma unroll
        for (int r = 0; r < 4; ++r) {
            int row = wave * 16 + quad * 4 + r;
            S.P[row * 33 + lm]      = accP0[r] + S.Bwin[lm];
            S.P[row * 33 + 16 + lm] = accP1[r] + S.Bwin[16 + lm];
        }
        for (int idx = tid; idx < 64 * 80; idx += TPB) S.Wacc[idx] = 0.f;
        if (tid < 64) S.Act[tid] = 0;
        if (t < 512) {
            for (int idx = tid; idx < 192; idx += TPB)
                S.Xt[idx] = strokes[(idx / 3) * (512 * 3) + t * 3 + (idx % 3)];
        }
        __syncthreads();

        // phase 3: attention (computes w_{t-1}); skipped at t==0 (w starts at 0)
        if (t >= 1) {
            for (int idx = tid; idx < 640; idx += TPB) {
                int b = idx / 10;
                int k = idx - b * 10;
                float ka = S.Ka[idx] + __expf(S.P[b * 33 + 20 + k]);
                S.Ka[idx] = ka;
                S.Al[idx] = __expf(S.P[b * 33 + k]);
                float be  = __expf(S.P[b * 33 + 10 + k]);
                S.Be[idx] = be;
                float dmin = fmaxf(fmaxf(-ka, ka - 63.f), 0.f);
                if (be * dmin * dmin <= 36.f) atomicOr(&S.Act[b], 1);
            }
            __syncthreads();
            #pragma unroll 1
            for (int ii = 0; ii < 16; ++ii) {
                int pair = tid + TPB * ii;
                int b = pair >> 6;
                if (!S.Act[b]) continue;   // wave-uniform (b constant per wave here)
                int u = pair & 63;
                float uu = (float)u;
                float s = 0.f;
                #pragma unroll
                for (int k = 0; k < 10; ++k) {
                    float d   = S.Ka[b * 10 + k] - uu;
                    float arg = -S.Be[b * 10 + k] * d * d;
                    s = fmaf(S.Al[b * 10 + k], __expf(arg), s);
                }
                float val = s * S.Maskv[b * 64 + u];
                if (val != 0.f)
                    atomicAdd(&S.Wacc[b * 80 + (int)S.Sent[b * 64 + u]], val);
            }
            __syncthreads();
            for (int idx = tid; idx < 64 * 80; idx += TPB)
                S.wBf[(idx / 80) * 104 + (idx % 80)] = (__bf16)S.Wacc[idx];
            if (blk < 64) {
                for (int n = tid; n < 80; n += TPB)
                    out[16777216 + blk * (512 * 80) + (t - 1) * 80 + n] = S.Wacc[blk * 80 + n];
            }
            __syncthreads();
        }

        if (t < 512) {
            // phase 4: w-part of gates (3 K-chunks, zero-padded to 96)
            const __bf16* wrow = S.wBf + myb * 104 + quad * 8;
            #pragma unroll
            for (int kc = 0; kc < 3; ++kc) {
                bf16x8 a  = *(const bf16x8*)(wrow + kc * 32);
                bf16x8 bg = *(const bf16x8*)(&S.bG[((16 + kc) * 64 + lane) * 8]);
                accG = __builtin_amdgcn_mfma_f32_16x16x32_bf16(a, bg, accG, 0, 0, 0);
            }
            // phase 5: add x-part, scatter gates, LSTM pointwise, publish h_t
            #pragma unroll
            for (int r = 0; r < 4; ++r) {
                int row = wave * 16 + quad * 4 + r;
                float v = accG[r]
                        + S.Xt[row * 3 + 0] * S.Wx[lm * 3 + 0]
                        + S.Xt[row * 3 + 1] * S.Wx[lm * 3 + 1]
                        + S.Xt[row * 3 + 2] * S.Wx[lm * 3 + 2];
                S.Gt[row * 17 + lm] = v;
            }
            __syncthreads();
            {
                int b  = tid >> 2;
                int ml = tid & 3;
                float gi = S.Gt[b * 17 + ml];
                float gf = S.Gt[b * 17 + 4 + ml];
                float gg = S.Gt[b * 17 + 8 + ml];
                float go = S.Gt[b * 17 + 12 + ml];
                float c  = sigf(gf) * c_state + sigf(gi) * tanh_fast(gg);
                c_state  = c;
                float h  = sigf(go) * tanh_fast(c);
                int colm = blk * 4 + ml;
                hbuf[(t & 1) * (64 * 512) + b * 512 + colm] = (__bf16)h;
                out[b * (512 * 512) + t * 512 + colm] = h;
            }
            grid_barrier(bar, bar + 1);
        }
    }
}

extern "C" void kernel_launch(void* const* d_in, const int* in_sizes, int n_in,
                              void* d_out, int out_size, void* d_ws, size_t ws_size,
                              hipStream_t stream) {
    const float* strokes   = (const float*)d_in[0];
    const int*   sentences = (const int*)d_in[1];
    const float* smask     = (const float*)d_in[2];
    const float* Wih       = (const float*)d_in[3];
    const float* Whh       = (const float*)d_in[4];
    const float* bih       = (const float*)d_in[5];
    const float* bhh       = (const float*)d_in[6];
    const float* Wwin      = (const float*)d_in[7];
    const float* bwin      = (const float*)d_in[8];
    float* out  = (float*)d_out;
    __bf16* hbuf = (__bf16*)d_ws;
    int* bar    = (int*)((char*)d_ws + 131072);

    init_ws_kernel<<<129, TPB, 0, stream>>>((int*)d_ws);
    lstm_attn<<<GRID_BLOCKS, TPB, 0, stream>>>(strokes, sentences, smask, Wih, Whh,
                                               bih, bhh, Wwin, bwin, out, hbuf, bar);
}

// Round 2
// 7028.299 us; speedup vs baseline: 1.6787x; 1.6787x over previous
//
#include <hip/hip_runtime.h>
#include <hip/hip_bf16.h>

// LSTM + Gaussian attention (Graves), B=64, T=512, H=512, K=10, NC=80, U=64.
// 64 persistent blocks x 256 threads, each owns 8 h-cols (32 gate cols).
// Cross-block h broadcast via MALL-coherent (volatile sc0/sc1) accesses;
// grid barrier = waitcnt + relaxed agent atomics (no L2 flush/invalidate).
// All MFMA B-fragments (W_hh, W_ih[w-part], W_win) live in registers.

#define GRID_BLOCKS 64
#define TPB 256

typedef __attribute__((ext_vector_type(8))) __bf16 bf16x8;
typedef __attribute__((ext_vector_type(4))) float f32x4;
typedef __attribute__((ext_vector_type(2))) float f32x2;

struct Smem {
    alignas(16) __bf16 wBf[64 * 104];  // w (attention) bf16, padded stride 104
    float P[64 * 33];                  // window pre-acts (30 cols), stride 33
    float Gt[64 * 33];                 // gates scatter (32 cols), stride 33
    float Al[640];
    float Be[640];
    float Ka[640];                     // kappa (replicated per block)
    float Wacc[64 * 80];               // w accumulator fp32
    float Xt[192];                     // x_t staged
    float Maskv[4096];
    float Wx[96];                      // x-part weights, 32 cols x 3
    float Bsum[32];
    float Bwin[32];
    int   Act[64];
    unsigned char Sent[4096];
};

__device__ __forceinline__ float sigf(float x) {
    return 1.f / (1.f + __expf(-x));
}
__device__ __forceinline__ float tanh_fast(float x) {
    float xx = fminf(fmaxf(x, -15.f), 15.f);
    float e = __expf(2.f * xx);
    return (e - 1.f) / (e + 1.f);
}

// Flush-free grid barrier: all cross-block data goes through the MALL (sc0 sc1),
// so no L2 writeback/invalidate is needed -- only store-ack drain + relaxed atomics.
__device__ __forceinline__ void grid_barrier(int* cnt, int* gen) {
    __syncthreads();   // compiler drains each wave's vmcnt before s_barrier
    if (threadIdx.x == 0) {
        __builtin_amdgcn_s_waitcnt(0);
        int g = __hip_atomic_load(gen, __ATOMIC_RELAXED, __HIP_MEMORY_SCOPE_AGENT);
        int old = __hip_atomic_fetch_add(cnt, 1, __ATOMIC_RELAXED, __HIP_MEMORY_SCOPE_AGENT);
        if (old == GRID_BLOCKS - 1) {
            __hip_atomic_store(cnt, 0, __ATOMIC_RELAXED, __HIP_MEMORY_SCOPE_AGENT);
            __hip_atomic_fetch_add(gen, 1, __ATOMIC_RELAXED, __HIP_MEMORY_SCOPE_AGENT);
        } else {
            while (__hip_atomic_load(gen, __ATOMIC_RELAXED, __HIP_MEMORY_SCOPE_AGENT) == g) {
                __builtin_amdgcn_s_sleep(2);
            }
        }
    }
    __syncthreads();
}

__global__ void init_ws_kernel(int* ws) {
    // zero h double-buffer (131072 B) + barrier (8 B)
    int idx = blockIdx.x * TPB + threadIdx.x;
    if (idx < 32770) ws[idx] = 0;
}

__global__ void __launch_bounds__(TPB, 1) lstm_attn(
    const float* __restrict__ strokes,    // [64][512][3]
    const int*   __restrict__ sentences,  // [64][64]
    const float* __restrict__ smask,      // [64][64]
    const float* __restrict__ Wih,        // [2048][83]
    const float* __restrict__ Whh,        // [2048][512]
    const float* __restrict__ bih,        // [2048]
    const float* __restrict__ bhh,        // [2048]
    const float* __restrict__ Wwin,      // [30][512]
    const float* __restrict__ bwin,      // [30]
    float* __restrict__ out,             // hs [64][512][512] ++ ws [64][512][80]
    unsigned short* __restrict__ hbuf,   // [2][64][512] bf16 bits (MALL-coherent)
    int* __restrict__ bar)
{
    __shared__ Smem S;
    const int tid  = threadIdx.x;
    const int blk  = blockIdx.x;
    const int lane = tid & 63;
    const int wave = tid >> 6;
    const int lm   = lane & 15;   // MFMA n-col within tile / A row
    const int quad = lane >> 4;   // MFMA k-block
    const int myb  = wave * 16 + lm;
    const int koff = quad * 8;

    // ---------------- one-time init: B-fragments -> REGISTERS ----------------
    bf16x8 rbG[2][19];   // gates: per tile, 16 h-chunks + 3 w-chunks
    bf16x8 rbP[2][16];   // window: 2 n-tiles x 16 h-chunks
    #pragma unroll
    for (int tau = 0; tau < 2; ++tau) {
        const int colg = (lm >> 2) * 512 + blk * 8 + tau * 4 + (lm & 3);
        const float* wr = Whh + colg * 512;
        #pragma unroll
        for (int kc = 0; kc < 16; ++kc) {
            f32x4 lo = *(const f32x4*)(wr + kc * 32 + koff);
            f32x4 hi = *(const f32x4*)(wr + kc * 32 + koff + 4);
            bf16x8 b;
            b[0] = (__bf16)lo[0]; b[1] = (__bf16)lo[1];
            b[2] = (__bf16)lo[2]; b[3] = (__bf16)lo[3];
            b[4] = (__bf16)hi[0]; b[5] = (__bf16)hi[1];
            b[6] = (__bf16)hi[2]; b[7] = (__bf16)hi[3];
            rbG[tau][kc] = b;
        }
        #pragma unroll
        for (int kc = 0; kc < 3; ++kc) {
            bf16x8 b;
            #pragma unroll
            for (int j = 0; j < 8; ++j) {
                int k = kc * 32 + koff + j;
                b[j] = (__bf16)((k < 80) ? Wih[colg * 83 + 3 + k] : 0.f);
            }
            rbG[tau][16 + kc] = b;
        }
    }
    #pragma unroll
    for (int nt = 0; nt < 2; ++nt) {
        const int r = nt * 16 + lm;
        #pragma unroll
        for (int kc = 0; kc < 16; ++kc) {
            bf16x8 b;
            if (r < 30) {
                f32x4 lo = *(const f32x4*)(Wwin + r * 512 + kc * 32 + koff);
                f32x4 hi = *(const f32x4*)(Wwin + r * 512 + kc * 32 + koff + 4);
                b[0] = (__bf16)lo[0]; b[1] = (__bf16)lo[1];
                b[2] = (__bf16)lo[2]; b[3] = (__bf16)lo[3];
                b[4] = (__bf16)hi[0]; b[5] = (__bf16)hi[1];
                b[6] = (__bf16)hi[2]; b[7] = (__bf16)hi[3];
            } else {
                #pragma unroll
                for (int j = 0; j < 8; ++j) b[j] = (__bf16)0.f;
            }
            rbP[nt][kc] = b;
        }
    }

    // ---------------- one-time init: LDS ----------------
    for (int idx = tid; idx < 4096; idx += TPB) {
        S.Sent[idx]  = (unsigned char)sentences[idx];
        S.Maskv[idx] = smask[idx];
    }
    if (tid < 32) {
        int tau = tid >> 4, m = tid & 15;
        int colg = (m >> 2) * 512 + blk * 8 + tau * 4 + (m & 3);
        S.Bsum[tid] = bih[colg] + bhh[colg];
        S.Wx[tid * 3 + 0] = Wih[colg * 83 + 0];
        S.Wx[tid * 3 + 1] = Wih[colg * 83 + 1];
        S.Wx[tid * 3 + 2] = Wih[colg * 83 + 2];
        S.Bwin[tid] = (tid < 30) ? bwin[tid] : 0.f;
    }
    for (int idx = tid; idx < 640; idx += TPB) S.Ka[idx] = 0.f;
    for (int idx = tid; idx < 64 * 104; idx += TPB) S.wBf[idx] = (__bf16)0.f;
    float cst0 = 0.f, cst1 = 0.f;  // cell state: batch tid>>2, h-cols 2*(tid&3)+{0,1}
    __syncthreads();

    // ---------------- main time loop ----------------
    for (int t = 0; t <= 512; ++t) {
        // phase 1: gates + window pre-acts, one shared A stream (MALL-coherent h)
        const unsigned short* hb = hbuf + ((t + 1) & 1) * 32768 + myb * 512 + koff;
        float bs0 = S.Bsum[lm], bs1 = S.Bsum[16 + lm];
        f32x4 accG0 = {bs0, bs0, bs0, bs0};
        f32x4 accG1 = {bs1, bs1, bs1, bs1};
        f32x4 accP0 = {0.f, 0.f, 0.f, 0.f};
        f32x4 accP1 = {0.f, 0.f, 0.f, 0.f};
        #pragma unroll
        for (int kc = 0; kc < 16; ++kc) {
            f32x4 raw = *(const volatile f32x4*)(hb + kc * 32);   // sc0 sc1
            bf16x8 a = __builtin_bit_cast(bf16x8, raw);
            accG0 = __builtin_amdgcn_mfma_f32_16x16x32_bf16(a, rbG[0][kc], accG0, 0, 0, 0);
            accG1 = __builtin_amdgcn_mfma_f32_16x16x32_bf16(a, rbG[1][kc], accG1, 0, 0, 0);
            accP0 = __builtin_amdgcn_mfma_f32_16x16x32_bf16(a, rbP[0][kc], accP0, 0, 0, 0);
            accP1 = __builtin_amdgcn_mfma_f32_16x16x32_bf16(a, rbP[1][kc], accP1, 0, 0, 0);
        }

        // phase 2: scatter p (+b_win), zero w accumulator, clear Act, stage x_t
        #pragma unroll
        for (int r = 0; r < 4; ++r) {
            int row = wave * 16 + quad * 4 + r;
            S.P[row * 33 + lm]      = accP0[r] + S.Bwin[lm];
            S.P[row * 33 + 16 + lm] = accP1[r] + S.Bwin[16 + lm];
        }
        for (int idx = tid; idx < 64 * 80; idx += TPB) S.Wacc[idx] = 0.f;
        if (tid < 64) S.Act[tid] = 0;
        if (t < 512) {
            for (int idx = tid; idx < 192; idx += TPB)
                S.Xt[idx] = strokes[(idx / 3) * 1536 + t * 3 + (idx % 3)];
        }
        __syncthreads();

        // phase 3: attention -> w_{t-1}; skipped at t==0 (w starts 0)
        if (t >= 1) {
            for (int idx = tid; idx < 640; idx += TPB) {
                int b = idx / 10;
                int k = idx - b * 10;
                float ka = S.Ka[idx] + __expf(S.P[b * 33 + 20 + k]);
                S.Ka[idx] = ka;
                S.Al[idx] = __expf(S.P[b * 33 + k]);
                float be  = __expf(S.P[b * 33 + 10 + k]);
                S.Be[idx] = be;
                float dmin = fmaxf(fmaxf(-ka, ka - 63.f), 0.f);
                if (be * dmin * dmin <= 36.f) atomicOr(&S.Act[b], 1);
            }
            __syncthreads();
            #pragma unroll 1
            for (int ii = 0; ii < 16; ++ii) {
                int pair = tid + TPB * ii;
                int b = pair >> 6;
                if (!S.Act[b]) continue;   // wave-uniform
                int u = pair & 63;
                float uu = (float)u;
                float s = 0.f;
                #pragma unroll
                for (int k = 0; k < 10; ++k) {
                    float d   = S.Ka[b * 10 + k] - uu;
                    float arg = -S.Be[b * 10 + k] * d * d;
                    s = fmaf(S.Al[b * 10 + k], __expf(arg), s);
                }
                float val = s * S.Maskv[b * 64 + u];
                if (val != 0.f)
                    atomicAdd(&S.Wacc[b * 80 + (int)S.Sent[b * 64 + u]], val);
            }
            __syncthreads();
            for (int idx = tid; idx < 64 * 80; idx += TPB)
                S.wBf[(idx / 80) * 104 + (idx % 80)] = (__bf16)S.Wacc[idx];
            {   // each block owns one batch's ws output row
                for (int n = tid; n < 80; n += TPB)
                    out[16777216 + blk * (512 * 80) + (t - 1) * 80 + n] = S.Wacc[blk * 80 + n];
            }
            __syncthreads();
        }

        if (t < 512) {
            // phase 4: w-part of gates (K padded 80->96)
            const __bf16* wrow = S.wBf + myb * 104 + koff;
            #pragma unroll
            for (int kc = 0; kc < 3; ++kc) {
                bf16x8 a = *(const bf16x8*)(wrow + kc * 32);
                accG0 = __builtin_amdgcn_mfma_f32_16x16x32_bf16(a, rbG[0][16 + kc], accG0, 0, 0, 0);
                accG1 = __builtin_amdgcn_mfma_f32_16x16x32_bf16(a, rbG[1][16 + kc], accG1, 0, 0, 0);
            }
            // phase 5: add x-part, scatter gates
            #pragma unroll
            for (int r = 0; r < 4; ++r) {
                int row = wave * 16 + quad * 4 + r;
                float x0 = S.Xt[row * 3 + 0], x1 = S.Xt[row * 3 + 1], x2 = S.Xt[row * 3 + 2];
                S.Gt[row * 33 + lm] = accG0[r]
                    + x0 * S.Wx[lm * 3 + 0] + x1 * S.Wx[lm * 3 + 1] + x2 * S.Wx[lm * 3 + 2];
                S.Gt[row * 33 + 16 + lm] = accG1[r]
                    + x0 * S.Wx[(16 + lm) * 3 + 0] + x1 * S.Wx[(16 + lm) * 3 + 1]
                    + x2 * S.Wx[(16 + lm) * 3 + 2];
            }
            __syncthreads();
            // phase 6: LSTM pointwise, publish h_t (coherent) + out (cached)
            {
                int b  = tid >> 2;
                int a2 = tid & 3;
                float hv0, hv1;
                {
                    int c = 2 * a2, tau = c >> 2, mm = c & 3;
                    const float* g = &S.Gt[b * 33 + tau * 16];
                    float cc = sigf(g[4 + mm]) * cst0 + sigf(g[mm]) * tanh_fast(g[8 + mm]);
                    cst0 = cc;
                    hv0 = sigf(g[12 + mm]) * tanh_fast(cc);
                }
                {
                    int c = 2 * a2 + 1, tau = c >> 2, mm = c & 3;
                    const float* g = &S.Gt[b * 33 + tau * 16];
                    float cc = sigf(g[4 + mm]) * cst1 + sigf(g[mm]) * tanh_fast(g[8 + mm]);
                    cst1 = cc;
                    hv1 = sigf(g[12 + mm]) * tanh_fast(cc);
                }
                union { __bf16 q[2]; unsigned u; } pk;
                pk.q[0] = (__bf16)hv0; pk.q[1] = (__bf16)hv1;
                ((volatile unsigned*)hbuf)[(t & 1) * 16384 + b * 256 + blk * 4 + a2] = pk.u;
                f32x2 ho = {hv0, hv1};
                *(f32x2*)(out + b * 262144 + t * 512 + blk * 8 + 2 * a2) = ho;
            }
            grid_barrier(bar, bar + 1);
        }
    }
}

extern "C" void kernel_launch(void* const* d_in, const int* in_sizes, int n_in,
                              void* d_out, int out_size, void* d_ws, size_t ws_size,
                              hipStream_t stream) {
    const float* strokes   = (const float*)d_in[0];
    const int*   sentences = (const int*)d_in[1];
    const float* smask     = (const float*)d_in[2];
    const float* Wih       = (const float*)d_in[3];
    const float* Whh       = (const float*)d_in[4];
    const float* bih       = (const float*)d_in[5];
    const float* bhh       = (const float*)d_in[6];
    const float* Wwin      = (const float*)d_in[7];
    const float* bwin      = (const float*)d_in[8];
    float* out = (float*)d_out;
    unsigned short* hbuf = (unsigned short*)d_ws;
    int* bar = (int*)((char*)d_ws + 131072);

    init_ws_kernel<<<129, TPB, 0, stream>>>((int*)d_ws);
    lstm_attn<<<GRID_BLOCKS, TPB, 0, stream>>>(strokes, sentences, smask, Wih, Whh,
                                               bih, bhh, Wwin, bwin, out, hbuf, bar);
}

// Round 3
// 6457.214 us; speedup vs baseline: 1.8272x; 1.0884x over previous
//
#include <hip/hip_runtime.h>
#include <hip/hip_bf16.h>

// LSTM + Gaussian attention (Graves), B=64, T=512, H=512, K=10, NC=80, U=64.
// 64 persistent blocks x 256 threads, each owns 8 h-cols (32 gate cols).
// Cross-block h broadcast via MALL-coherent (volatile sc0/sc1) accesses.
// Synchronization: per-block epoch flags (no central atomic counter).
//   producer: h stores -> __syncthreads (drains vmcnt for all waves) -> flag[blk]=t+1
//   consumer: each wave polls all 64 flags with one coalesced lane-parallel load.
// All MFMA B-fragments (W_hh, W_ih[w-part], W_win) live in registers.

#define GRID_BLOCKS 64
#define TPB 256

typedef __attribute__((ext_vector_type(8))) __bf16 bf16x8;
typedef __attribute__((ext_vector_type(4))) float f32x4;
typedef __attribute__((ext_vector_type(2))) float f32x2;

struct Smem {
    alignas(16) __bf16 wBf[64 * 104];  // w (attention) bf16, padded stride 104
    float P[64 * 33];                  // window pre-acts (30 cols), stride 33
    float Gt[64 * 33];                 // gates scatter (32 cols), stride 33
    float Al[640];
    float Be[640];
    float Ka[640];                     // kappa (replicated per block)
    float Wacc[64 * 80];               // w accumulator fp32
    float Xt[192];                     // x_t staged
    float Maskv[4096];
    float Wx[96];                      // x-part weights, 32 cols x 3
    float Bsum[32];
    float Bwin[32];
    int   Act[64];
    unsigned char Sent[4096];
};

__device__ __forceinline__ float sigf(float x) {
    return 1.f / (1.f + __expf(-x));
}
__device__ __forceinline__ float tanh_fast(float x) {
    float xx = fminf(fmaxf(x, -15.f), 15.f);
    float e = __expf(2.f * xx);
    return (e - 1.f) / (e + 1.f);
}

__global__ void init_ws_kernel(int* ws) {
    // zero h double-buffer (131072 B) + 64 epoch flags (256 B)
    int idx = blockIdx.x * TPB + threadIdx.x;
    if (idx < 32832) ws[idx] = 0;
}

__global__ void __launch_bounds__(TPB, 1) lstm_attn(
    const float* __restrict__ strokes,    // [64][512][3]
    const int*   __restrict__ sentences,  // [64][64]
    const float* __restrict__ smask,      // [64][64]
    const float* __restrict__ Wih,        // [2048][83]
    const float* __restrict__ Whh,        // [2048][512]
    const float* __restrict__ bih,        // [2048]
    const float* __restrict__ bhh,        // [2048]
    const float* __restrict__ Wwin,      // [30][512]
    const float* __restrict__ bwin,      // [30]
    float* __restrict__ out,             // hs [64][512][512] ++ ws [64][512][80]
    unsigned short* __restrict__ hbuf,   // [2][64][512] bf16 bits (MALL-coherent)
    int* __restrict__ flags)             // [64] epoch flags
{
    __shared__ Smem S;
    const int tid  = threadIdx.x;
    const int blk  = blockIdx.x;
    const int lane = tid & 63;
    const int wave = tid >> 6;
    const int lm   = lane & 15;   // MFMA n-col within tile / A row
    const int quad = lane >> 4;   // MFMA k-block
    const int myb  = wave * 16 + lm;
    const int koff = quad * 8;
    volatile int* vflags = (volatile int*)flags;

    // ---------------- one-time init: B-fragments -> REGISTERS ----------------
    bf16x8 rbG[2][19];   // gates: per tile, 16 h-chunks + 3 w-chunks
    bf16x8 rbP[2][16];   // window: 2 n-tiles x 16 h-chunks
    #pragma unroll
    for (int tau = 0; tau < 2; ++tau) {
        const int colg = (lm >> 2) * 512 + blk * 8 + tau * 4 + (lm & 3);
        const float* wr = Whh + colg * 512;
        #pragma unroll
        for (int kc = 0; kc < 16; ++kc) {
            f32x4 lo = *(const f32x4*)(wr + kc * 32 + koff);
            f32x4 hi = *(const f32x4*)(wr + kc * 32 + koff + 4);
            bf16x8 b;
            b[0] = (__bf16)lo[0]; b[1] = (__bf16)lo[1];
            b[2] = (__bf16)lo[2]; b[3] = (__bf16)lo[3];
            b[4] = (__bf16)hi[0]; b[5] = (__bf16)hi[1];
            b[6] = (__bf16)hi[2]; b[7] = (__bf16)hi[3];
            rbG[tau][kc] = b;
        }
        #pragma unroll
        for (int kc = 0; kc < 3; ++kc) {
            bf16x8 b;
            #pragma unroll
            for (int j = 0; j < 8; ++j) {
                int k = kc * 32 + koff + j;
                b[j] = (__bf16)((k < 80) ? Wih[colg * 83 + 3 + k] : 0.f);
            }
            rbG[tau][16 + kc] = b;
        }
    }
    #pragma unroll
    for (int nt = 0; nt < 2; ++nt) {
        const int r = nt * 16 + lm;
        #pragma unroll
        for (int kc = 0; kc < 16; ++kc) {
            bf16x8 b;
            if (r < 30) {
                f32x4 lo = *(const f32x4*)(Wwin + r * 512 + kc * 32 + koff);
                f32x4 hi = *(const f32x4*)(Wwin + r * 512 + kc * 32 + koff + 4);
                b[0] = (__bf16)lo[0]; b[1] = (__bf16)lo[1];
                b[2] = (__bf16)lo[2]; b[3] = (__bf16)lo[3];
                b[4] = (__bf16)hi[0]; b[5] = (__bf16)hi[1];
                b[6] = (__bf16)hi[2]; b[7] = (__bf16)hi[3];
            } else {
                #pragma unroll
                for (int j = 0; j < 8; ++j) b[j] = (__bf16)0.f;
            }
            rbP[nt][kc] = b;
        }
    }

    // ---------------- one-time init: LDS ----------------
    for (int idx = tid; idx < 4096; idx += TPB) {
        S.Sent[idx]  = (unsigned char)sentences[idx];
        S.Maskv[idx] = smask[idx];
    }
    if (tid < 32) {
        int tau = tid >> 4, m = tid & 15;
        int colg = (m >> 2) * 512 + blk * 8 + tau * 4 + (m & 3);
        S.Bsum[tid] = bih[colg] + bhh[colg];
        S.Wx[tid * 3 + 0] = Wih[colg * 83 + 0];
        S.Wx[tid * 3 + 1] = Wih[colg * 83 + 1];
        S.Wx[tid * 3 + 2] = Wih[colg * 83 + 2];
        S.Bwin[tid] = (tid < 30) ? bwin[tid] : 0.f;
    }
    for (int idx = tid; idx < 640; idx += TPB) S.Ka[idx] = 0.f;
    for (int idx = tid; idx < 64 * 104; idx += TPB) S.wBf[idx] = (__bf16)0.f;
    float cst0 = 0.f, cst1 = 0.f;  // cell state: batch tid>>2, h-cols 2*(tid&3)+{0,1}
    __syncthreads();

    // ---------------- main time loop ----------------
    for (int t = 0; t <= 512; ++t) {
        // phase 0: every wave independently waits for all producers of h_{t-1}
        if (t >= 1) {
            while (!__all(vflags[lane] >= t)) {
                __builtin_amdgcn_s_sleep(1);
            }
        }
        // phase 1: gates + window pre-acts, one shared A stream (MALL-coherent h)
        const unsigned short* hb = hbuf + ((t + 1) & 1) * 32768 + myb * 512 + koff;
        float bs0 = S.Bsum[lm], bs1 = S.Bsum[16 + lm];
        f32x4 accG0 = {bs0, bs0, bs0, bs0};
        f32x4 accG1 = {bs1, bs1, bs1, bs1};
        f32x4 accP0 = {0.f, 0.f, 0.f, 0.f};
        f32x4 accP1 = {0.f, 0.f, 0.f, 0.f};
        #pragma unroll
        for (int kc = 0; kc < 16; ++kc) {
            f32x4 raw = *(const volatile f32x4*)(hb + kc * 32);   // sc0 sc1
            bf16x8 a = __builtin_bit_cast(bf16x8, raw);
            accG0 = __builtin_amdgcn_mfma_f32_16x16x32_bf16(a, rbG[0][kc], accG0, 0, 0, 0);
            accG1 = __builtin_amdgcn_mfma_f32_16x16x32_bf16(a, rbG[1][kc], accG1, 0, 0, 0);
            accP0 = __builtin_amdgcn_mfma_f32_16x16x32_bf16(a, rbP[0][kc], accP0, 0, 0, 0);
            accP1 = __builtin_amdgcn_mfma_f32_16x16x32_bf16(a, rbP[1][kc], accP1, 0, 0, 0);
        }

        // phase 2: scatter p (+b_win), zero w accumulator, clear Act, stage x_t
        #pragma unroll
        for (int r = 0; r < 4; ++r) {
            int row = wave * 16 + quad * 4 + r;
            S.P[row * 33 + lm]      = accP0[r] + S.Bwin[lm];
            S.P[row * 33 + 16 + lm] = accP1[r] + S.Bwin[16 + lm];
        }
        for (int idx = tid; idx < 64 * 80; idx += TPB) S.Wacc[idx] = 0.f;
        if (tid < 64) S.Act[tid] = 0;
        if (t < 512) {
            for (int idx = tid; idx < 192; idx += TPB)
                S.Xt[idx] = strokes[(idx / 3) * 1536 + t * 3 + (idx % 3)];
        }
        __syncthreads();

        // phase 3: attention -> w_{t-1}; skipped at t==0 (w starts 0)
        if (t >= 1) {
            for (int idx = tid; idx < 640; idx += TPB) {
                int b = idx / 10;
                int k = idx - b * 10;
                float ka = S.Ka[idx] + __expf(S.P[b * 33 + 20 + k]);
                S.Ka[idx] = ka;
                S.Al[idx] = __expf(S.P[b * 33 + k]);
                float be  = __expf(S.P[b * 33 + 10 + k]);
                S.Be[idx] = be;
                float dmin = fmaxf(fmaxf(-ka, ka - 63.f), 0.f);
                if (be * dmin * dmin <= 36.f) atomicOr(&S.Act[b], 1);
            }
            __syncthreads();
            #pragma unroll 1
            for (int ii = 0; ii < 16; ++ii) {
                int pair = tid + TPB * ii;
                int b = pair >> 6;
                if (!S.Act[b]) continue;   // wave-uniform
                int u = pair & 63;
                float uu = (float)u;
                float s = 0.f;
                #pragma unroll
                for (int k = 0; k < 10; ++k) {
                    float d   = S.Ka[b * 10 + k] - uu;
                    float arg = -S.Be[b * 10 + k] * d * d;
                    s = fmaf(S.Al[b * 10 + k], __expf(arg), s);
                }
                float val = s * S.Maskv[b * 64 + u];
                if (val != 0.f)
                    atomicAdd(&S.Wacc[b * 80 + (int)S.Sent[b * 64 + u]], val);
            }
            __syncthreads();
            for (int idx = tid; idx < 64 * 80; idx += TPB)
                S.wBf[(idx / 80) * 104 + (idx % 80)] = (__bf16)S.Wacc[idx];
            {   // each block owns one batch's ws output row
                for (int n = tid; n < 80; n += TPB)
                    out[16777216 + blk * (512 * 80) + (t - 1) * 80 + n] = S.Wacc[blk * 80 + n];
            }
            __syncthreads();
        }

        if (t < 512) {
            // phase 4: w-part of gates (K padded 80->96)
            const __bf16* wrow = S.wBf + myb * 104 + koff;
            #pragma unroll
            for (int kc = 0; kc < 3; ++kc) {
                bf16x8 a = *(const bf16x8*)(wrow + kc * 32);
                accG0 = __builtin_amdgcn_mfma_f32_16x16x32_bf16(a, rbG[0][16 + kc], accG0, 0, 0, 0);
                accG1 = __builtin_amdgcn_mfma_f32_16x16x32_bf16(a, rbG[1][16 + kc], accG1, 0, 0, 0);
            }
            // phase 5: add x-part, scatter gates
            #pragma unroll
            for (int r = 0; r < 4; ++r) {
                int row = wave * 16 + quad * 4 + r;
                float x0 = S.Xt[row * 3 + 0], x1 = S.Xt[row * 3 + 1], x2 = S.Xt[row * 3 + 2];
                S.Gt[row * 33 + lm] = accG0[r]
                    + x0 * S.Wx[lm * 3 + 0] + x1 * S.Wx[lm * 3 + 1] + x2 * S.Wx[lm * 3 + 2];
                S.Gt[row * 33 + 16 + lm] = accG1[r]
                    + x0 * S.Wx[(16 + lm) * 3 + 0] + x1 * S.Wx[(16 + lm) * 3 + 1]
                    + x2 * S.Wx[(16 + lm) * 3 + 2];
            }
            __syncthreads();
            // phase 6: LSTM pointwise, publish h_t (coherent) + out (cached)
            {
                int b  = tid >> 2;
                int a2 = tid & 3;
                float hv0, hv1;
                {
                    int c = 2 * a2, tau = c >> 2, mm = c & 3;
                    const float* g = &S.Gt[b * 33 + tau * 16];
                    float cc = sigf(g[4 + mm]) * cst0 + sigf(g[mm]) * tanh_fast(g[8 + mm]);
                    cst0 = cc;
                    hv0 = sigf(g[12 + mm]) * tanh_fast(cc);
                }
                {
                    int c = 2 * a2 + 1, tau = c >> 2, mm = c & 3;
                    const float* g = &S.Gt[b * 33 + tau * 16];
                    float cc = sigf(g[4 + mm]) * cst1 + sigf(g[mm]) * tanh_fast(g[8 + mm]);
                    cst1 = cc;
                    hv1 = sigf(g[12 + mm]) * tanh_fast(cc);
                }
                union { __bf16 q[2]; unsigned u; } pk;
                pk.q[0] = (__bf16)hv0; pk.q[1] = (__bf16)hv1;
                ((volatile unsigned*)hbuf)[(t & 1) * 16384 + b * 256 + blk * 4 + a2] = pk.u;
                f32x2 ho = {hv0, hv1};
                *(f32x2*)(out + b * 262144 + t * 512 + blk * 8 + 2 * a2) = ho;
            }
            // producer release: __syncthreads drains vmcnt(0) for ALL waves
            // (compiler-guaranteed before s_barrier), then publish epoch.
            __syncthreads();
            if (tid == 0) vflags[blk] = t + 1;
        }
    }
}

extern "C" void kernel_launch(void* const* d_in, const int* in_sizes, int n_in,
                              void* d_out, int out_size, void* d_ws, size_t ws_size,
                              hipStream_t stream) {
    const float* strokes   = (const float*)d_in[0];
    const int*   sentences = (const int*)d_in[1];
    const float* smask     = (const float*)d_in[2];
    const float* Wih       = (const float*)d_in[3];
    const float* Whh       = (const float*)d_in[4];
    const float* bih       = (const float*)d_in[5];
    const float* bhh       = (const float*)d_in[6];
    const float* Wwin      = (const float*)d_in[7];
    const float* bwin      = (const float*)d_in[8];
    float* out = (float*)d_out;
    unsigned short* hbuf = (unsigned short*)d_ws;
    int* flags = (int*)((char*)d_ws + 131072);

    init_ws_kernel<<<129, TPB, 0, stream>>>((int*)d_ws);
    lstm_attn<<<GRID_BLOCKS, TPB, 0, stream>>>(strokes, sentences, smask, Wih, Whh,
                                               bih, bhh, Wwin, bwin, out, hbuf, flags);
}

// Round 5
// 4231.161 us; speedup vs baseline: 2.7885x; 1.5261x over previous
//
#include <hip/hip_runtime.h>
#include <hip/hip_bf16.h>

// LSTM + Gaussian attention (Graves), B=64, T=512, H=512, K=10, NC=80, U=64.
// 64 persistent blocks x 256 threads, each block owns 8 h-cols (32 gate cols).
// Wave w of each block owns batches [16w,16w+16) for ALL intra-step phases
// (MFMA rows, attention, pointwise) -> phases are wave-local, only ONE
// __syncthreads per step (pre-flag drain).
// Cross-block h broadcast: MALL-coherent sc0/sc1; the 16 h loads are batched
// in one asm block (single round trip). Epoch-flag sync, no atomics.
// R5 fix: S.Wacc zero-initialized (R4 accumulated into uninitialized LDS at t=1).

#define GRID_BLOCKS 64
#define TPB 256

typedef __attribute__((ext_vector_type(8))) __bf16 bf16x8;
typedef __attribute__((ext_vector_type(4))) float f32x4;
typedef __attribute__((ext_vector_type(2))) float f32x2;

struct Smem {
    alignas(16) __bf16 wBf[64 * 104];  // w (attention) bf16, padded stride 104
    float P[64 * 33];                  // window pre-acts (30 cols), stride 33
    float Gt[64 * 33];                 // gates scatter (32 cols), stride 33
    float Al[640];
    float Be[640];
    float Ka[640];                     // kappa (replicated per block)
    float Wacc[64 * 80];               // w accumulator fp32
    float Xt[192];                     // x_t staged, [b][3]
    float Maskv[4096];
    float Wx[96];                      // x-part weights, 32 cols x 3
    float Bsum[32];
    float Bwin[32];
    int   Act[64];
    unsigned char Sent[4096];
};

__device__ __forceinline__ float sigf(float x) {
    return 1.f / (1.f + __expf(-x));
}
__device__ __forceinline__ float tanh_fast(float x) {
    float xx = fminf(fmaxf(x, -15.f), 15.f);
    float e = __expf(2.f * xx);
    return (e - 1.f) / (e + 1.f);
}

__global__ void init_ws_kernel(int* ws) {
    // zero h double-buffer (131072 B) + 64 epoch flags (256 B)
    int idx = blockIdx.x * TPB + threadIdx.x;
    if (idx < 32832) ws[idx] = 0;
}

__global__ void __launch_bounds__(TPB, 1) lstm_attn(
    const float* __restrict__ strokes,    // [64][512][3]
    const int*   __restrict__ sentences,  // [64][64]
    const float* __restrict__ smask,      // [64][64]
    const float* __restrict__ Wih,        // [2048][83]
    const float* __restrict__ Whh,        // [2048][512]
    const float* __restrict__ bih,        // [2048]
    const float* __restrict__ bhh,        // [2048]
    const float* __restrict__ Wwin,      // [30][512]
    const float* __restrict__ bwin,      // [30]
    float* __restrict__ out,             // hs [64][512][512] ++ ws [64][512][80]
    unsigned short* __restrict__ hbuf,   // [2][64][512] bf16 bits (MALL-coherent)
    int* __restrict__ flags)             // [64] epoch flags
{
    __shared__ Smem S;
    const int tid  = threadIdx.x;
    const int blk  = blockIdx.x;
    const int lane = tid & 63;
    const int wave = tid >> 6;
    const int lm   = lane & 15;   // MFMA n-col within tile / A row
    const int quad = lane >> 4;   // MFMA k-block
    const int myb  = wave * 16 + lm;
    const int koff = quad * 8;
    volatile int* vflags = (volatile int*)flags;

    // ---------------- one-time init: B-fragments -> REGISTERS ----------------
    bf16x8 rbG[2][19];   // gates: per tile, 16 h-chunks + 3 w-chunks
    bf16x8 rbP[2][16];   // window: 2 n-tiles x 16 h-chunks
    #pragma unroll
    for (int tau = 0; tau < 2; ++tau) {
        const int colg = (lm >> 2) * 512 + blk * 8 + tau * 4 + (lm & 3);
        const float* wr = Whh + colg * 512;
        #pragma unroll
        for (int kc = 0; kc < 16; ++kc) {
            f32x4 lo = *(const f32x4*)(wr + kc * 32 + koff);
            f32x4 hi = *(const f32x4*)(wr + kc * 32 + koff + 4);
            bf16x8 b;
            b[0] = (__bf16)lo[0]; b[1] = (__bf16)lo[1];
            b[2] = (__bf16)lo[2]; b[3] = (__bf16)lo[3];
            b[4] = (__bf16)hi[0]; b[5] = (__bf16)hi[1];
            b[6] = (__bf16)hi[2]; b[7] = (__bf16)hi[3];
            rbG[tau][kc] = b;
        }
        #pragma unroll
        for (int kc = 0; kc < 3; ++kc) {
            bf16x8 b;
            #pragma unroll
            for (int j = 0; j < 8; ++j) {
                int k = kc * 32 + koff + j;
                b[j] = (__bf16)((k < 80) ? Wih[colg * 83 + 3 + k] : 0.f);
            }
            rbG[tau][16 + kc] = b;
        }
    }
    #pragma unroll
    for (int nt = 0; nt < 2; ++nt) {
        const int r = nt * 16 + lm;
        #pragma unroll
        for (int kc = 0; kc < 16; ++kc) {
            bf16x8 b;
            if (r < 30) {
                f32x4 lo = *(const f32x4*)(Wwin + r * 512 + kc * 32 + koff);
                f32x4 hi = *(const f32x4*)(Wwin + r * 512 + kc * 32 + koff + 4);
                b[0] = (__bf16)lo[0]; b[1] = (__bf16)lo[1];
                b[2] = (__bf16)lo[2]; b[3] = (__bf16)lo[3];
                b[4] = (__bf16)hi[0]; b[5] = (__bf16)hi[1];
                b[6] = (__bf16)hi[2]; b[7] = (__bf16)hi[3];
            } else {
                #pragma unroll
                for (int j = 0; j < 8; ++j) b[j] = (__bf16)0.f;
            }
            rbP[nt][kc] = b;
        }
    }

    // ---------------- one-time init: LDS ----------------
    for (int idx = tid; idx < 4096; idx += TPB) {
        S.Sent[idx]  = (unsigned char)sentences[idx];
        S.Maskv[idx] = smask[idx];
    }
    if (tid < 32) {
        int tau = tid >> 4, m = tid & 15;
        int colg = (m >> 2) * 512 + blk * 8 + tau * 4 + (m & 3);
        S.Bsum[tid] = bih[colg] + bhh[colg];
        S.Wx[tid * 3 + 0] = Wih[colg * 83 + 0];
        S.Wx[tid * 3 + 1] = Wih[colg * 83 + 1];
        S.Wx[tid * 3 + 2] = Wih[colg * 83 + 2];
        S.Bwin[tid] = (tid < 30) ? bwin[tid] : 0.f;
    }
    for (int idx = tid; idx < 640; idx += TPB) S.Ka[idx] = 0.f;
    for (int idx = tid; idx < 5120; idx += TPB) S.Wacc[idx] = 0.f;   // R5 FIX
    for (int idx = tid; idx < 64 * 104; idx += TPB) S.wBf[idx] = (__bf16)0.f;
    float cst0 = 0.f, cst1 = 0.f;  // cell state: batch wave*16+(lane>>2), cols 2*(lane&3)+{0,1}
    __syncthreads();

    // per-lane loop-invariant constants (hoisted out of LDS)
    const float bs0 = S.Bsum[lm], bs1 = S.Bsum[16 + lm];
    const float bw0 = S.Bwin[lm], bw1 = S.Bwin[16 + lm];
    float wx[6];
    #pragma unroll
    for (int m = 0; m < 3; ++m) {
        wx[m]     = S.Wx[lm * 3 + m];
        wx[3 + m] = S.Wx[(16 + lm) * 3 + m];
    }
    const int pb  = wave * 16 + (lane >> 2);  // pointwise batch
    const int pa2 = lane & 3;                 // pointwise col pair
    bool waccDirty = false;

    // ---------------- main time loop ----------------
    for (int t = 0; t <= 512; ++t) {
        // phase 0: every wave independently waits for all producers of h_{t-1}
        if (t >= 1) {
            while (!__all(vflags[lane] >= t)) { }
        }
        // phase 1: batched MALL-coherent h loads -- ONE round trip
        const unsigned short* hb = hbuf + ((t + 1) & 1) * 32768 + myb * 512 + koff;
        f32x4 h0,h1,h2,h3,h4,h5,h6,h7,h8,h9,h10,h11,h12,h13,h14,h15;
        asm volatile(
            "global_load_dwordx4 %0, %16, off sc0 sc1\n\t"
            "global_load_dwordx4 %1, %16, off offset:64 sc0 sc1\n\t"
            "global_load_dwordx4 %2, %16, off offset:128 sc0 sc1\n\t"
            "global_load_dwordx4 %3, %16, off offset:192 sc0 sc1\n\t"
            "global_load_dwordx4 %4, %16, off offset:256 sc0 sc1\n\t"
            "global_load_dwordx4 %5, %16, off offset:320 sc0 sc1\n\t"
            "global_load_dwordx4 %6, %16, off offset:384 sc0 sc1\n\t"
            "global_load_dwordx4 %7, %16, off offset:448 sc0 sc1\n\t"
            "global_load_dwordx4 %8, %16, off offset:512 sc0 sc1\n\t"
            "global_load_dwordx4 %9, %16, off offset:576 sc0 sc1\n\t"
            "global_load_dwordx4 %10, %16, off offset:640 sc0 sc1\n\t"
            "global_load_dwordx4 %11, %16, off offset:704 sc0 sc1\n\t"
            "global_load_dwordx4 %12, %16, off offset:768 sc0 sc1\n\t"
            "global_load_dwordx4 %13, %16, off offset:832 sc0 sc1\n\t"
            "global_load_dwordx4 %14, %16, off offset:896 sc0 sc1\n\t"
            "global_load_dwordx4 %15, %16, off offset:960 sc0 sc1\n\t"
            "s_waitcnt vmcnt(0)"
            : "=&v"(h0), "=&v"(h1), "=&v"(h2), "=&v"(h3),
              "=&v"(h4), "=&v"(h5), "=&v"(h6), "=&v"(h7),
              "=&v"(h8), "=&v"(h9), "=&v"(h10), "=&v"(h11),
              "=&v"(h12), "=&v"(h13), "=&v"(h14), "=&v"(h15)
            : "v"(hb)
            : "memory");

        // stage x_t for this wave's batches (off critical path, L2-cached)
        if (t < 512 && lane < 48) {
            int gi = wave * 48 + lane;
            S.Xt[gi] = strokes[(gi / 3) * 1536 + t * 3 + (gi % 3)];
        }

        // MFMAs: window first (feeds the long attention chain), then gates
        f32x4 accG0 = {bs0, bs0, bs0, bs0};
        f32x4 accG1 = {bs1, bs1, bs1, bs1};
        f32x4 accP0 = {0.f, 0.f, 0.f, 0.f};
        f32x4 accP1 = {0.f, 0.f, 0.f, 0.f};
        #define KSTEP(R, I) { bf16x8 a = __builtin_bit_cast(bf16x8, R); \
            accP0 = __builtin_amdgcn_mfma_f32_16x16x32_bf16(a, rbP[0][I], accP0, 0, 0, 0); \
            accP1 = __builtin_amdgcn_mfma_f32_16x16x32_bf16(a, rbP[1][I], accP1, 0, 0, 0); \
            accG0 = __builtin_amdgcn_mfma_f32_16x16x32_bf16(a, rbG[0][I], accG0, 0, 0, 0); \
            accG1 = __builtin_amdgcn_mfma_f32_16x16x32_bf16(a, rbG[1][I], accG1, 0, 0, 0); }
        KSTEP(h0, 0)  KSTEP(h1, 1)  KSTEP(h2, 2)  KSTEP(h3, 3)
        KSTEP(h4, 4)  KSTEP(h5, 5)  KSTEP(h6, 6)  KSTEP(h7, 7)
        KSTEP(h8, 8)  KSTEP(h9, 9)  KSTEP(h10, 10) KSTEP(h11, 11)
        KSTEP(h12, 12) KSTEP(h13, 13) KSTEP(h14, 14) KSTEP(h15, 15)
        #undef KSTEP

        // phase 2: scatter p (+b_win) -- rows are wave-local
        #pragma unroll
        for (int r = 0; r < 4; ++r) {
            int row = wave * 16 + quad * 4 + r;
            S.P[row * 33 + lm]      = accP0[r] + bw0;
            S.P[row * 33 + 16 + lm] = accP1[r] + bw1;
        }
        __builtin_amdgcn_wave_barrier();

        // phase 3: attention (wave-local, NO block barrier) -> w_{t-1}
        bool waveAny = false;
        if (t >= 1) {
            if (lane < 16) S.Act[wave * 16 + lane] = 0;
            __builtin_amdgcn_wave_barrier();
            #pragma unroll
            for (int it = 0; it < 3; ++it) {
                int idx = lane + it * 64;
                if (idx < 160) {
                    int bl = idx / 10, k = idx - bl * 10;
                    int gb = wave * 16 + bl, ad = gb * 10 + k;
                    float ka = S.Ka[ad] + __expf(S.P[gb * 33 + 20 + k]);
                    S.Ka[ad] = ka;
                    S.Al[ad] = __expf(S.P[gb * 33 + k]);
                    float be = __expf(S.P[gb * 33 + 10 + k]);
                    S.Be[ad] = be;
                    float dmin = fmaxf(fmaxf(-ka, ka - 63.f), 0.f);
                    if (be * dmin * dmin <= 36.f) atomicOr(&S.Act[gb], 1);
                }
            }
            __builtin_amdgcn_wave_barrier();
            int actv = (lane < 16) ? S.Act[wave * 16 + lane] : 0;
            waveAny = __any(actv != 0);
            if (waccDirty) {
                for (int i = lane; i < 1280; i += 64) S.Wacc[wave * 1280 + i] = 0.f;
            }
            __builtin_amdgcn_wave_barrier();
            if (waveAny) {
                #pragma unroll 1
                for (int ii = 0; ii < 16; ++ii) {
                    int gb = wave * 16 + ii;
                    if (!S.Act[gb]) continue;   // wave-uniform
                    float uu = (float)lane;
                    float s = 0.f;
                    #pragma unroll
                    for (int k = 0; k < 10; ++k) {
                        float d = S.Ka[gb * 10 + k] - uu;
                        s = fmaf(S.Al[gb * 10 + k], __expf(-S.Be[gb * 10 + k] * d * d), s);
                    }
                    float val = s * S.Maskv[gb * 64 + lane];
                    if (val != 0.f)
                        atomicAdd(&S.Wacc[gb * 80 + (int)S.Sent[gb * 64 + lane]], val);
                }
            }
            __builtin_amdgcn_wave_barrier();
            if (waveAny || waccDirty) {
                for (int i = lane; i < 1280; i += 64) {
                    int bl = i / 80, n = i - bl * 80;
                    S.wBf[(wave * 16 + bl) * 104 + n] = (__bf16)S.Wacc[wave * 1280 + i];
                }
            }
            __builtin_amdgcn_wave_barrier();
        }

        float hv0 = 0.f, hv1 = 0.f;
        if (t < 512) {
            // phase 4: w-part of gates (skip when wBf is all-zero)
            if (waveAny) {
                const __bf16* wrow = S.wBf + myb * 104 + koff;
                #pragma unroll
                for (int kc = 0; kc < 3; ++kc) {
                    bf16x8 a = *(const bf16x8*)(wrow + kc * 32);
                    accG0 = __builtin_amdgcn_mfma_f32_16x16x32_bf16(a, rbG[0][16 + kc], accG0, 0, 0, 0);
                    accG1 = __builtin_amdgcn_mfma_f32_16x16x32_bf16(a, rbG[1][16 + kc], accG1, 0, 0, 0);
                }
            }
            // phase 5: add x-part, scatter gates (wave-local rows)
            #pragma unroll
            for (int r = 0; r < 4; ++r) {
                int row = wave * 16 + quad * 4 + r;
                float x0 = S.Xt[row * 3 + 0], x1 = S.Xt[row * 3 + 1], x2 = S.Xt[row * 3 + 2];
                S.Gt[row * 33 + lm]      = accG0[r] + x0 * wx[0] + x1 * wx[1] + x2 * wx[2];
                S.Gt[row * 33 + 16 + lm] = accG1[r] + x0 * wx[3] + x1 * wx[4] + x2 * wx[5];
            }
            __builtin_amdgcn_wave_barrier();
            // phase 6: LSTM pointwise (reads wave-local Gt rows), publish h_t
            {
                const float* g = &S.Gt[pb * 33];
                {
                    int c = 2 * pa2, tau = c >> 2, mm = c & 3;
                    const float* gg = g + tau * 16;
                    float cc = sigf(gg[4 + mm]) * cst0 + sigf(gg[mm]) * tanh_fast(gg[8 + mm]);
                    cst0 = cc;
                    hv0 = sigf(gg[12 + mm]) * tanh_fast(cc);
                }
                {
                    int c = 2 * pa2 + 1, tau = c >> 2, mm = c & 3;
                    const float* gg = g + tau * 16;
                    float cc = sigf(gg[4 + mm]) * cst1 + sigf(gg[mm]) * tanh_fast(gg[8 + mm]);
                    cst1 = cc;
                    hv1 = sigf(gg[12 + mm]) * tanh_fast(cc);
                }
                union { __bf16 q[2]; unsigned u; } pk;
                pk.q[0] = (__bf16)hv0; pk.q[1] = (__bf16)hv1;
                ((volatile unsigned*)hbuf)[(t & 1) * 16384 + pb * 256 + blk * 4 + pa2] = pk.u;
            }
        }
        waccDirty = waveAny;

        if (t < 512) {
            // ONE block barrier per step: drains all waves' h stores (vmcnt),
            // then publish the epoch flag.
            __syncthreads();
            if (tid == 0) vflags[blk] = t + 1;
            // outputs AFTER the publish -- off the inter-block critical path
            f32x2 ho = {hv0, hv1};
            *(f32x2*)(out + pb * 262144 + t * 512 + blk * 8 + 2 * pa2) = ho;
        }
        if (t >= 1 && wave == (blk >> 4)) {
            // this block stores ws for batch blk (owned by this wave)
            for (int n = lane; n < 80; n += 64)
                out[16777216 + blk * 40960 + (t - 1) * 80 + n] = S.Wacc[blk * 80 + n];
        }
    }
}

extern "C" void kernel_launch(void* const* d_in, const int* in_sizes, int n_in,
                              void* d_out, int out_size, void* d_ws, size_t ws_size,
                              hipStream_t stream) {
    const float* strokes   = (const float*)d_in[0];
    const int*   sentences = (const int*)d_in[1];
    const float* smask     = (const float*)d_in[2];
    const float* Wih       = (const float*)d_in[3];
    const float* Whh       = (const float*)d_in[4];
    const float* bih       = (const float*)d_in[5];
    const float* bhh       = (const float*)d_in[6];
    const float* Wwin      = (const float*)d_in[7];
    const float* bwin      = (const float*)d_in[8];
    float* out = (float*)d_out;
    unsigned short* hbuf = (unsigned short*)d_ws;
    int* flags = (int*)((char*)d_ws + 131072);

    init_ws_kernel<<<129, TPB, 0, stream>>>((int*)d_ws);
    lstm_attn<<<GRID_BLOCKS, TPB, 0, stream>>>(strokes, sentences, smask, Wih, Whh,
                                               bih, bhh, Wwin, bwin, out, hbuf, flags);
}

// Round 6
// 3809.636 us; speedup vs baseline: 3.0971x; 1.1106x over previous
//
#include <hip/hip_runtime.h>
#include <hip/hip_bf16.h>

// LSTM + Gaussian attention (Graves), B=64, T=512, H=512, K=10, NC=80, U=64.
// 64 persistent blocks x 256 threads, each block owns 8 h-cols (32 gate cols).
// Wave w of each block owns batches [16w,16w+16) for ALL intra-step phases.
// Cross-block h broadcast: MALL-coherent sc0/sc1; 16 h loads batched in one
// asm block (single round trip).
// R6 sync: PER-WAVE epoch flags (padded 64B/block, no producer barrier);
// only wave 0 polls (s_sleep backoff), one release __syncthreads per step.
// x_t double-buffered, prefetched by waves 1-3 while wave 0 polls.

#define GRID_BLOCKS 64
#define TPB 256

typedef __attribute__((ext_vector_type(8))) __bf16 bf16x8;
typedef __attribute__((ext_vector_type(4))) float f32x4;
typedef __attribute__((ext_vector_type(2))) float f32x2;
typedef __attribute__((ext_vector_type(4))) int i32x4;

struct Smem {
    alignas(16) __bf16 wBf[64 * 104];  // w (attention) bf16, padded stride 104
    float P[64 * 33];                  // window pre-acts (30 cols), stride 33
    float Gt[64 * 33];                 // gates scatter (32 cols), stride 33
    float Al[640];
    float Be[640];
    float Ka[640];                     // kappa (replicated per block)
    float Wacc[64 * 80];               // w accumulator fp32
    float Xt[2 * 192];                 // x_t staged, double-buffered [buf][b][3]
    float Maskv[4096];
    float Wx[96];                      // x-part weights, 32 cols x 3
    float Bsum[32];
    float Bwin[32];
    int   Act[64];
    unsigned char Sent[4096];
};

__device__ __forceinline__ float sigf(float x) {
    return 1.f / (1.f + __expf(-x));
}
__device__ __forceinline__ float tanh_fast(float x) {
    float xx = fminf(fmaxf(x, -15.f), 15.f);
    float e = __expf(2.f * xx);
    return (e - 1.f) / (e + 1.f);
}

__global__ void init_ws_kernel(int* ws) {
    // zero h double-buffer (131072 B) + 64*64B padded wave-flags (4096 B)
    int idx = blockIdx.x * TPB + threadIdx.x;
    if (idx < 33792) ws[idx] = 0;
}

__global__ void __launch_bounds__(TPB, 1) lstm_attn(
    const float* __restrict__ strokes,    // [64][512][3]
    const int*   __restrict__ sentences,  // [64][64]
    const float* __restrict__ smask,      // [64][64]
    const float* __restrict__ Wih,        // [2048][83]
    const float* __restrict__ Whh,        // [2048][512]
    const float* __restrict__ bih,        // [2048]
    const float* __restrict__ bhh,        // [2048]
    const float* __restrict__ Wwin,      // [30][512]
    const float* __restrict__ bwin,      // [30]
    float* __restrict__ out,             // hs [64][512][512] ++ ws [64][512][80]
    unsigned short* __restrict__ hbuf,   // [2][64][512] bf16 bits (MALL-coherent)
    int* __restrict__ flags)             // [64 blocks][16 ints (64B)]: 4 wave-flags each
{
    __shared__ Smem S;
    const int tid  = threadIdx.x;
    const int blk  = blockIdx.x;
    const int lane = tid & 63;
    const int wave = tid >> 6;
    const int lm   = lane & 15;   // MFMA n-col within tile / A row
    const int quad = lane >> 4;   // MFMA k-block
    const int myb  = wave * 16 + lm;
    const int koff = quad * 8;

    // ---------------- one-time init: B-fragments -> REGISTERS ----------------
    bf16x8 rbG[2][19];   // gates: per tile, 16 h-chunks + 3 w-chunks
    bf16x8 rbP[2][16];   // window: 2 n-tiles x 16 h-chunks
    #pragma unroll
    for (int tau = 0; tau < 2; ++tau) {
        const int colg = (lm >> 2) * 512 + blk * 8 + tau * 4 + (lm & 3);
        const float* wr = Whh + colg * 512;
        #pragma unroll
        for (int kc = 0; kc < 16; ++kc) {
            f32x4 lo = *(const f32x4*)(wr + kc * 32 + koff);
            f32x4 hi = *(const f32x4*)(wr + kc * 32 + koff + 4);
            bf16x8 b;
            b[0] = (__bf16)lo[0]; b[1] = (__bf16)lo[1];
            b[2] = (__bf16)lo[2]; b[3] = (__bf16)lo[3];
            b[4] = (__bf16)hi[0]; b[5] = (__bf16)hi[1];
            b[6] = (__bf16)hi[2]; b[7] = (__bf16)hi[3];
            rbG[tau][kc] = b;
        }
        #pragma unroll
        for (int kc = 0; kc < 3; ++kc) {
            bf16x8 b;
            #pragma unroll
            for (int j = 0; j < 8; ++j) {
                int k = kc * 32 + koff + j;
                b[j] = (__bf16)((k < 80) ? Wih[colg * 83 + 3 + k] : 0.f);
            }
            rbG[tau][16 + kc] = b;
        }
    }
    #pragma unroll
    for (int nt = 0; nt < 2; ++nt) {
        const int r = nt * 16 + lm;
        #pragma unroll
        for (int kc = 0; kc < 16; ++kc) {
            bf16x8 b;
            if (r < 30) {
                f32x4 lo = *(const f32x4*)(Wwin + r * 512 + kc * 32 + koff);
                f32x4 hi = *(const f32x4*)(Wwin + r * 512 + kc * 32 + koff + 4);
                b[0] = (__bf16)lo[0]; b[1] = (__bf16)lo[1];
                b[2] = (__bf16)lo[2]; b[3] = (__bf16)lo[3];
                b[4] = (__bf16)hi[0]; b[5] = (__bf16)hi[1];
                b[6] = (__bf16)hi[2]; b[7] = (__bf16)hi[3];
            } else {
                #pragma unroll
                for (int j = 0; j < 8; ++j) b[j] = (__bf16)0.f;
            }
            rbP[nt][kc] = b;
        }
    }

    // ---------------- one-time init: LDS ----------------
    for (int idx = tid; idx < 4096; idx += TPB) {
        S.Sent[idx]  = (unsigned char)sentences[idx];
        S.Maskv[idx] = smask[idx];
    }
    if (tid < 32) {
        int tau = tid >> 4, m = tid & 15;
        int colg = (m >> 2) * 512 + blk * 8 + tau * 4 + (m & 3);
        S.Bsum[tid] = bih[colg] + bhh[colg];
        S.Wx[tid * 3 + 0] = Wih[colg * 83 + 0];
        S.Wx[tid * 3 + 1] = Wih[colg * 83 + 1];
        S.Wx[tid * 3 + 2] = Wih[colg * 83 + 2];
        S.Bwin[tid] = (tid < 30) ? bwin[tid] : 0.f;
    }
    for (int idx = tid; idx < 640; idx += TPB) S.Ka[idx] = 0.f;
    for (int idx = tid; idx < 5120; idx += TPB) S.Wacc[idx] = 0.f;
    for (int idx = tid; idx < 64 * 104; idx += TPB) S.wBf[idx] = (__bf16)0.f;
    if (tid < 192) S.Xt[tid] = strokes[(tid / 3) * 1536 + (tid % 3)];  // x_0 -> buf 0
    float cst0 = 0.f, cst1 = 0.f;  // cell state: batch wave*16+(lane>>2), cols 2*(lane&3)+{0,1}
    __syncthreads();

    // per-lane loop-invariant constants (hoisted out of LDS)
    const float bs0 = S.Bsum[lm], bs1 = S.Bsum[16 + lm];
    const float bw0 = S.Bwin[lm], bw1 = S.Bwin[16 + lm];
    float wx[6];
    #pragma unroll
    for (int m = 0; m < 3; ++m) {
        wx[m]     = S.Wx[lm * 3 + m];
        wx[3 + m] = S.Wx[(16 + lm) * 3 + m];
    }
    const int pb  = wave * 16 + (lane >> 2);  // pointwise batch
    const int pa2 = lane & 3;                 // pointwise col pair
    bool waccDirty = false;

    // ---------------- main time loop ----------------
    for (int t = 0; t <= 512; ++t) {
        // phase 0: wave 0 polls all 64 blocks' wave-flags; barrier releases all
        if (t >= 1) {
            if (wave == 0) {
                const volatile i32x4* vf =
                    (const volatile i32x4*)((const char*)flags + lane * 64);
                for (;;) {
                    i32x4 v = *vf;
                    int m01 = v.x < v.y ? v.x : v.y;
                    int m23 = v.z < v.w ? v.z : v.w;
                    int mm  = m01 < m23 ? m01 : m23;
                    if (__all(mm >= t)) break;
                    __builtin_amdgcn_s_sleep(1);
                }
            }
            __syncthreads();
        }
        // phase 1: batched MALL-coherent h loads -- ONE round trip
        const unsigned short* hb = hbuf + ((t + 1) & 1) * 32768 + myb * 512 + koff;
        f32x4 h0,h1,h2,h3,h4,h5,h6,h7,h8,h9,h10,h11,h12,h13,h14,h15;
        asm volatile(
            "global_load_dwordx4 %0, %16, off sc0 sc1\n\t"
            "global_load_dwordx4 %1, %16, off offset:64 sc0 sc1\n\t"
            "global_load_dwordx4 %2, %16, off offset:128 sc0 sc1\n\t"
            "global_load_dwordx4 %3, %16, off offset:192 sc0 sc1\n\t"
            "global_load_dwordx4 %4, %16, off offset:256 sc0 sc1\n\t"
            "global_load_dwordx4 %5, %16, off offset:320 sc0 sc1\n\t"
            "global_load_dwordx4 %6, %16, off offset:384 sc0 sc1\n\t"
            "global_load_dwordx4 %7, %16, off offset:448 sc0 sc1\n\t"
            "global_load_dwordx4 %8, %16, off offset:512 sc0 sc1\n\t"
            "global_load_dwordx4 %9, %16, off offset:576 sc0 sc1\n\t"
            "global_load_dwordx4 %10, %16, off offset:640 sc0 sc1\n\t"
            "global_load_dwordx4 %11, %16, off offset:704 sc0 sc1\n\t"
            "global_load_dwordx4 %12, %16, off offset:768 sc0 sc1\n\t"
            "global_load_dwordx4 %13, %16, off offset:832 sc0 sc1\n\t"
            "global_load_dwordx4 %14, %16, off offset:896 sc0 sc1\n\t"
            "global_load_dwordx4 %15, %16, off offset:960 sc0 sc1\n\t"
            "s_waitcnt vmcnt(0)"
            : "=&v"(h0), "=&v"(h1), "=&v"(h2), "=&v"(h3),
              "=&v"(h4), "=&v"(h5), "=&v"(h6), "=&v"(h7),
              "=&v"(h8), "=&v"(h9), "=&v"(h10), "=&v"(h11),
              "=&v"(h12), "=&v"(h13), "=&v"(h14), "=&v"(h15)
            : "v"(hb)
            : "memory");

        // MFMAs: window first (feeds the long attention chain), then gates
        f32x4 accG0 = {bs0, bs0, bs0, bs0};
        f32x4 accG1 = {bs1, bs1, bs1, bs1};
        f32x4 accP0 = {0.f, 0.f, 0.f, 0.f};
        f32x4 accP1 = {0.f, 0.f, 0.f, 0.f};
        #define KSTEP(R, I) { bf16x8 a = __builtin_bit_cast(bf16x8, R); \
            accP0 = __builtin_amdgcn_mfma_f32_16x16x32_bf16(a, rbP[0][I], accP0, 0, 0, 0); \
            accP1 = __builtin_amdgcn_mfma_f32_16x16x32_bf16(a, rbP[1][I], accP1, 0, 0, 0); \
            accG0 = __builtin_amdgcn_mfma_f32_16x16x32_bf16(a, rbG[0][I], accG0, 0, 0, 0); \
            accG1 = __builtin_amdgcn_mfma_f32_16x16x32_bf16(a, rbG[1][I], accG1, 0, 0, 0); }
        KSTEP(h0, 0)  KSTEP(h1, 1)  KSTEP(h2, 2)  KSTEP(h3, 3)
        KSTEP(h4, 4)  KSTEP(h5, 5)  KSTEP(h6, 6)  KSTEP(h7, 7)
        KSTEP(h8, 8)  KSTEP(h9, 9)  KSTEP(h10, 10) KSTEP(h11, 11)
        KSTEP(h12, 12) KSTEP(h13, 13) KSTEP(h14, 14) KSTEP(h15, 15)
        #undef KSTEP

        // phase 2: scatter p (+b_win) -- rows are wave-local
        #pragma unroll
        for (int r = 0; r < 4; ++r) {
            int row = wave * 16 + quad * 4 + r;
            S.P[row * 33 + lm]      = accP0[r] + bw0;
            S.P[row * 33 + 16 + lm] = accP1[r] + bw1;
        }
        __builtin_amdgcn_wave_barrier();

        // phase 3: attention (wave-local, NO block barrier) -> w_{t-1}
        bool waveAny = false;
        if (t >= 1) {
            if (lane < 16) S.Act[wave * 16 + lane] = 0;
            __builtin_amdgcn_wave_barrier();
            #pragma unroll
            for (int it = 0; it < 3; ++it) {
                int idx = lane + it * 64;
                if (idx < 160) {
                    int bl = idx / 10, k = idx - bl * 10;
                    int gb = wave * 16 + bl, ad = gb * 10 + k;
                    float ka = S.Ka[ad] + __expf(S.P[gb * 33 + 20 + k]);
                    S.Ka[ad] = ka;
                    S.Al[ad] = __expf(S.P[gb * 33 + k]);
                    float be = __expf(S.P[gb * 33 + 10 + k]);
                    S.Be[ad] = be;
                    float dmin = fmaxf(fmaxf(-ka, ka - 63.f), 0.f);
                    if (be * dmin * dmin <= 36.f) atomicOr(&S.Act[gb], 1);
                }
            }
            __builtin_amdgcn_wave_barrier();
            int actv = (lane < 16) ? S.Act[wave * 16 + lane] : 0;
            waveAny = __any(actv != 0);
            if (waccDirty) {
                for (int i = lane; i < 1280; i += 64) S.Wacc[wave * 1280 + i] = 0.f;
            }
            __builtin_amdgcn_wave_barrier();
            if (waveAny) {
                #pragma unroll 1
                for (int ii = 0; ii < 16; ++ii) {
                    int gb = wave * 16 + ii;
                    if (!S.Act[gb]) continue;   // wave-uniform
                    float uu = (float)lane;
                    float s = 0.f;
                    #pragma unroll
                    for (int k = 0; k < 10; ++k) {
                        float d = S.Ka[gb * 10 + k] - uu;
                        s = fmaf(S.Al[gb * 10 + k], __expf(-S.Be[gb * 10 + k] * d * d), s);
                    }
                    float val = s * S.Maskv[gb * 64 + lane];
                    if (val != 0.f)
                        atomicAdd(&S.Wacc[gb * 80 + (int)S.Sent[gb * 64 + lane]], val);
                }
            }
            __builtin_amdgcn_wave_barrier();
            if (waveAny || waccDirty) {
                for (int i = lane; i < 1280; i += 64) {
                    int bl = i / 80, n = i - bl * 80;
                    S.wBf[(wave * 16 + bl) * 104 + n] = (__bf16)S.Wacc[wave * 1280 + i];
                }
            }
            __builtin_amdgcn_wave_barrier();
        }

        float hv0 = 0.f, hv1 = 0.f;
        if (t < 512) {
            // phase 4: w-part of gates (skip when wBf is all-zero)
            if (waveAny) {
                const __bf16* wrow = S.wBf + myb * 104 + koff;
                #pragma unroll
                for (int kc = 0; kc < 3; ++kc) {
                    bf16x8 a = *(const bf16x8*)(wrow + kc * 32);
                    accG0 = __builtin_amdgcn_mfma_f32_16x16x32_bf16(a, rbG[0][16 + kc], accG0, 0, 0, 0);
                    accG1 = __builtin_amdgcn_mfma_f32_16x16x32_bf16(a, rbG[1][16 + kc], accG1, 0, 0, 0);
                }
            }
            // phase 5: add x-part, scatter gates (wave-local rows)
            const float* xb = &S.Xt[(t & 1) * 192];
            #pragma unroll
            for (int r = 0; r < 4; ++r) {
                int row = wave * 16 + quad * 4 + r;
                float x0 = xb[row * 3 + 0], x1 = xb[row * 3 + 1], x2 = xb[row * 3 + 2];
                S.Gt[row * 33 + lm]      = accG0[r] + x0 * wx[0] + x1 * wx[1] + x2 * wx[2];
                S.Gt[row * 33 + 16 + lm] = accG1[r] + x0 * wx[3] + x1 * wx[4] + x2 * wx[5];
            }
            __builtin_amdgcn_wave_barrier();
            // phase 6: LSTM pointwise (reads wave-local Gt rows), publish h_t
            {
                const float* g = &S.Gt[pb * 33];
                {
                    int c = 2 * pa2, tau = c >> 2, mm = c & 3;
                    const float* gg = g + tau * 16;
                    float cc = sigf(gg[4 + mm]) * cst0 + sigf(gg[mm]) * tanh_fast(gg[8 + mm]);
                    cst0 = cc;
                    hv0 = sigf(gg[12 + mm]) * tanh_fast(cc);
                }
                {
                    int c = 2 * pa2 + 1, tau = c >> 2, mm = c & 3;
                    const float* gg = g + tau * 16;
                    float cc = sigf(gg[4 + mm]) * cst1 + sigf(gg[mm]) * tanh_fast(gg[8 + mm]);
                    cst1 = cc;
                    hv1 = sigf(gg[12 + mm]) * tanh_fast(cc);
                }
                union { __bf16 q[2]; unsigned u; } pk;
                pk.q[0] = (__bf16)hv0; pk.q[1] = (__bf16)hv1;
                ((volatile unsigned*)hbuf)[(t & 1) * 16384 + pb * 256 + blk * 4 + pa2] = pk.u;
            }
            // producer release (PER WAVE): drain own h stores, publish wave-flag
            asm volatile("s_waitcnt vmcnt(0)" ::: "memory");
            if (lane == 0)
                *(volatile int*)((char*)flags + blk * 64 + wave * 4) = t + 1;
            // outputs + x prefetch AFTER the publish -- off the critical path
            {
                f32x2 ho = {hv0, hv1};
                *(f32x2*)(out + pb * 262144 + t * 512 + blk * 8 + 2 * pa2) = ho;
            }
            if (wave != 0 && t + 1 < 512) {
                int gi = (wave - 1) * 64 + lane;   // waves 1-3 cover all 192 values
                if (gi < 192)
                    S.Xt[((t + 1) & 1) * 192 + gi] =
                        strokes[(gi / 3) * 1536 + (t + 1) * 3 + (gi % 3)];
            }
        }
        waccDirty = waveAny;

        if (t >= 1 && wave == (blk >> 4)) {
            // this block stores ws for batch blk (owned by this wave)
            for (int n = lane; n < 80; n += 64)
                out[16777216 + blk * 40960 + (t - 1) * 80 + n] = S.Wacc[blk * 80 + n];
        }
    }
}

extern "C" void kernel_launch(void* const* d_in, const int* in_sizes, int n_in,
                              void* d_out, int out_size, void* d_ws, size_t ws_size,
                              hipStream_t stream) {
    const float* strokes   = (const float*)d_in[0];
    const int*   sentences = (const int*)d_in[1];
    const float* smask     = (const float*)d_in[2];
    const float* Wih       = (const float*)d_in[3];
    const float* Whh       = (const float*)d_in[4];
    const float* bih       = (const float*)d_in[5];
    const float* bhh       = (const float*)d_in[6];
    const float* Wwin      = (const float*)d_in[7];
    const float* bwin      = (const float*)d_in[8];
    float* out = (float*)d_out;
    unsigned short* hbuf = (unsigned short*)d_ws;
    int* flags = (int*)((char*)d_ws + 131072);

    init_ws_kernel<<<132, TPB, 0, stream>>>((int*)d_ws);
    lstm_attn<<<GRID_BLOCKS, TPB, 0, stream>>>(strokes, sentences, smask, Wih, Whh,
                                               bih, bhh, Wwin, bwin, out, hbuf, flags);
}